// Round 3
// baseline (321.617 us; speedup 1.0000x reference)
//
#include <hip/hip_runtime.h>

// CrossNet fused: out = initial * (X @ alphas) + X + bias
// B=16384 rows, D=2048 cols, fp32. One wave per row.
//
// R2/R3: single memory round-trip per wave. Preload X, initial, bias into
// registers BEFORE the shuffle reduction so every long-latency load is in
// flight during the dependent reduction chain. launch_bounds(256,2) lifts
// the VGPR cap (R1's 32-VGPR allocation forced an X re-load after the
// reduction -> second serialized round-trip -> 112us at 30% HBM).
// Non-temporal stores (via native vector type — HIP float4 class is not
// accepted by the builtin) keep the write stream from evicting LLC-warm
// inputs.

#define CN_D 2048
#define CN_ROWS 16384

typedef float vfloat4 __attribute__((ext_vector_type(4)));

__global__ __launch_bounds__(256, 2) void crossnet_kernel(
    const float* __restrict__ initial,
    const float* __restrict__ X,
    const float* __restrict__ alphas,
    const float* __restrict__ bias,
    float* __restrict__ out)
{
    const int wave = threadIdx.x >> 6;          // 0..3
    const int lane = threadIdx.x & 63;
    const int row  = (blockIdx.x << 2) + wave;  // 4 rows per block

    const vfloat4* __restrict__ Xrow = (const vfloat4*)(X       + (size_t)row * CN_D);
    const vfloat4* __restrict__ Irow = (const vfloat4*)(initial + (size_t)row * CN_D);
    const vfloat4* __restrict__ A4   = (const vfloat4*)alphas;  // (D,1) contiguous, L2-resident
    const vfloat4* __restrict__ B4   = (const vfloat4*)bias;    // L2-resident
    vfloat4*       __restrict__ Orow = (vfloat4*)(out + (size_t)row * CN_D);

    // D/4 = 512 float4 per row; 64 lanes x 8 chunks. Hold everything in regs.
    vfloat4 x[8], ini[8], bi[8];

    // Issue burst: 24 global loads in flight before any use.
#pragma unroll
    for (int k = 0; k < 8; ++k) {
        const int idx = (k << 6) + lane;        // lane-contiguous -> coalesced
        x[k]   = Xrow[idx];
        ini[k] = Irow[idx];
        bi[k]  = B4[idx];
    }

    // Dot against alphas with 2 accumulators for FMA ILP.
    float a0 = 0.0f, a1 = 0.0f;
#pragma unroll
    for (int k = 0; k < 8; k += 2) {
        const int i0 = (k << 6) + lane;
        const int i1 = ((k + 1) << 6) + lane;
        const vfloat4 p = A4[i0];
        const vfloat4 q = A4[i1];
        a0 = fmaf(x[k].x,   p.x, a0); a0 = fmaf(x[k].y,   p.y, a0);
        a0 = fmaf(x[k].z,   p.z, a0); a0 = fmaf(x[k].w,   p.w, a0);
        a1 = fmaf(x[k+1].x, q.x, a1); a1 = fmaf(x[k+1].y, q.y, a1);
        a1 = fmaf(x[k+1].z, q.z, a1); a1 = fmaf(x[k+1].w, q.w, a1);
    }
    float acc = a0 + a1;

    // 64-lane butterfly, broadcast from lane 0.
#pragma unroll
    for (int off = 32; off > 0; off >>= 1)
        acc += __shfl_down(acc, off, 64);
    const float scale = __shfl(acc, 0, 64);

    // Load-free epilogue; non-temporal stores (write-once stream).
#pragma unroll
    for (int k = 0; k < 8; ++k) {
        const int idx = (k << 6) + lane;
        vfloat4 o;
        o.x = fmaf(ini[k].x, scale, x[k].x + bi[k].x);
        o.y = fmaf(ini[k].y, scale, x[k].y + bi[k].y);
        o.z = fmaf(ini[k].z, scale, x[k].z + bi[k].z);
        o.w = fmaf(ini[k].w, scale, x[k].w + bi[k].w);
        __builtin_nontemporal_store(o, &Orow[idx]);
    }
}

extern "C" void kernel_launch(void* const* d_in, const int* in_sizes, int n_in,
                              void* d_out, int out_size, void* d_ws, size_t ws_size,
                              hipStream_t stream) {
    const float* initial = (const float*)d_in[0];
    const float* X       = (const float*)d_in[1];
    const float* alphas  = (const float*)d_in[2];
    const float* bias    = (const float*)d_in[3];
    float* out = (float*)d_out;

    crossnet_kernel<<<CN_ROWS / 4, 256, 0, stream>>>(initial, X, alphas, bias, out);
}